// Round 14
// baseline (310.522 us; speedup 1.0000x reference)
//
#include <hip/hip_runtime.h>
#include <stdint.h>

#define NSEQ 512
#define CH   128
#define NN   (NSEQ*NSEQ)   // 262144

typedef unsigned short u16;
typedef __attribute__((ext_vector_type(8))) short bf16x8;  // 8 bf16 = 4 VGPRs
typedef __attribute__((ext_vector_type(4))) float f32x4;

__device__ __forceinline__ u16 f2bf(float x){          // RNE
  uint32_t u = __float_as_uint(x);
  u += 0x7fffu + ((u >> 16) & 1u);
  return (u16)(u >> 16);
}
__device__ __forceinline__ float bf2f(u16 h){
  return __uint_as_float(((uint32_t)h) << 16);
}
__device__ __forceinline__ uint32_t cvtpk(float lo, float hi){  // bf16(lo)|bf16(hi)<<16
  uint32_t r;
  asm volatile("v_cvt_pk_bf16_f32 %0, %1, %2" : "=v"(r) : "v"(lo), "v"(hi));
  return r;
}
__device__ __forceinline__ float sigm(float x){
  return __builtin_amdgcn_rcpf(1.0f + __expf(-x));
}
__device__ __forceinline__ void gll16(const void* g, void* l){  // 16B global->LDS DMA
  __builtin_amdgcn_global_load_lds((const __attribute__((address_space(1))) void*)g,
                                   (__attribute__((address_space(3))) void*)l, 16, 0, 0);
}

// left/right tensor layout: [i (512)][kblk (8)][c (128)][kin (64)] u16
// offset = i*65536 + kblk*8192 + c*64 + kin   (flat row n = i*512 + kblk*64 + kin)

// ------------- k0: cast 6 weight matrices fp32 -> bf16 -------------
// slot order: 0=W_left 1=W_lgate 2=W_right 3=W_rgate 4=W_ogate 5=W_out
__global__ void k0_cvt(const float* __restrict__ w0, const float* __restrict__ w1,
                       const float* __restrict__ w2, const float* __restrict__ w3,
                       const float* __restrict__ w4, const float* __restrict__ w5,
                       u16* __restrict__ out)
{
  int mat = blockIdx.x >> 4;
  int blk = blockIdx.x & 15;
  const float* src = (mat==0)?w0:(mat==1)?w1:(mat==2)?w2:(mat==3)?w3:(mat==4)?w4:w5;
  int idx = (blk*256 + (int)threadIdx.x) * 4;
  float4 v = *(const float4*)(src + idx);
  uint2 pk;
  pk.x = cvtpk(v.x, v.y);
  pk.y = cvtpk(v.z, v.w);
  *(uint2*)(out + mat*16384 + idx) = pk;
}

// ------------- k1ab: FUSED LN(z) + 2 gated projections, 64 rows/block -----
// Single-tile blocks: LDS ~34.8KB -> 4 blocks/CU (was 52.7KB -> 3). Tests
// whether occupancy is the binding resource for the projection family.
__global__ __launch_bounds__(256) void k1ab_proj(
    const float* __restrict__ z, const float* __restrict__ pmask,
    const float* __restrict__ lnw, const float* __restrict__ lnb,
    const float* __restrict__ b_lg, const float* __restrict__ b_rg,
    const u16* __restrict__ wts, u16* __restrict__ znS,
    u16* __restrict__ left_t, u16* __restrict__ right_t)
{
  __shared__ __align__(16) u16 zn[64][136];     // 17.4 KB
  __shared__ __align__(16) u16 stg[4][2048];    // 16 KB (per-wave stage)
  __shared__ float lnw_s[128], lnb_s[128], mask_s[64];
  const int t = threadIdx.x;
  const int row0 = blockIdx.x * 64;
  const size_t tile_off = (size_t)(row0 >> 9)*65536 + (size_t)((row0 >> 6) & 7)*8192;

  if (t < 32)      ((float4*)lnw_s)[t]     = ((const float4*)lnw)[t];
  else if (t < 64) ((float4*)lnb_s)[t-32]  = ((const float4*)lnb)[t-32];
  else if (t < 80) ((float4*)mask_s)[t-64] = ((const float4*)(pmask + row0))[t-64];

  // lane-contiguous z loads: float4 idx e*256+t (1KB/instr)
  const float4* zt = (const float4*)(z + (size_t)row0 * CH);
  float4 v0[8];
  #pragma unroll
  for (int e=0;e<8;e++) v0[e] = zt[e*256 + t];
  __syncthreads();   // lnw_s/lnb_s/mask_s visible

  const int rsub = t >> 5;          // row sub-index within step
  const int c4   = (t & 31) * 4;    // this thread's 4 channels

  // LN: per step e, row = e*8+rsub; stats over the 32-lane half-group
  #pragma unroll
  for (int e=0;e<8;e++){
    float4 vv = v0[e];
    float s  = vv.x + vv.y + vv.z + vv.w;
    float sq = vv.x*vv.x + vv.y*vv.y + vv.z*vv.z + vv.w*vv.w;
    s += __shfl_xor(s,1);  sq += __shfl_xor(sq,1);
    s += __shfl_xor(s,2);  sq += __shfl_xor(sq,2);
    s += __shfl_xor(s,4);  sq += __shfl_xor(sq,4);
    s += __shfl_xor(s,8);  sq += __shfl_xor(sq,8);
    s += __shfl_xor(s,16); sq += __shfl_xor(sq,16);
    float mu = s * (1.f/128.f);
    float rstd = __builtin_amdgcn_rsqf(sq * (1.f/128.f) - mu*mu + 1e-5f);
    float y0 = (vv.x - mu)*rstd*lnw_s[c4+0] + lnb_s[c4+0];
    float y1 = (vv.y - mu)*rstd*lnw_s[c4+1] + lnb_s[c4+1];
    float y2 = (vv.z - mu)*rstd*lnw_s[c4+2] + lnb_s[c4+2];
    float y3 = (vv.w - mu)*rstd*lnw_s[c4+3] + lnb_s[c4+3];
    uint2 pk = make_uint2(cvtpk(y0,y1), cvtpk(y2,y3));
    ((uint2*)(znS + (size_t)row0*CH))[e*256 + t] = pk;   // coalesced 8B/lane
    int row = e*8 + rsub;
    *(uint2*)&zn[row][c4] = pk;
  }
  __syncthreads();   // zn ready

  const int lane = t & 63;
  const int w = t >> 6;
  const int lr = lane & 15;
  const int lg = lane >> 4;
  const int ow = w*32;
  const f32x4 zero4 = {0.f,0.f,0.f,0.f};

  // pass-A weights
  bf16x8 wl[8], wg[8];
  #pragma unroll
  for (int kk=0;kk<4;kk++)
    #pragma unroll
    for (int n=0;n<2;n++){
      int o = ow + n*16 + lr;
      wl[kk*2+n] = *(const bf16x8*)&wts[0*16384 + o*128 + kk*32 + lg*8];
      wg[kk*2+n] = *(const bf16x8*)&wts[1*16384 + o*128 + kk*32 + lg*8];
    }

  f32x4 acc1[4][2], acc2[4][2];
  #pragma unroll
  for (int mi=0;mi<4;mi++){ acc1[mi][0]=zero4; acc1[mi][1]=zero4; acc2[mi][0]=zero4; acc2[mi][1]=zero4; }
  #pragma unroll
  for (int kk=0;kk<4;kk++){
    bf16x8 a[4];
    #pragma unroll
    for (int mi=0;mi<4;mi++)
      a[mi] = *(const bf16x8*)&zn[mi*16 + lr][kk*32 + lg*8];
    #pragma unroll
    for (int n=0;n<2;n++)
      #pragma unroll
      for (int mi=0;mi<4;mi++){
        acc1[mi][n] = __builtin_amdgcn_mfma_f32_16x16x32_bf16(a[mi], wl[kk*2+n], acc1[mi][n], 0,0,0);
        acc2[mi][n] = __builtin_amdgcn_mfma_f32_16x16x32_bf16(a[mi], wg[kk*2+n], acc2[mi][n], 0,0,0);
      }
  }
  // prefetch pass-B weights
  bf16x8 wl2[8], wg2[8];
  #pragma unroll
  for (int kk=0;kk<4;kk++)
    #pragma unroll
    for (int n=0;n<2;n++){
      int o = ow + n*16 + lr;
      wl2[kk*2+n] = *(const bf16x8*)&wts[2*16384 + o*128 + kk*32 + lg*8];
      wg2[kk*2+n] = *(const bf16x8*)&wts[3*16384 + o*128 + kk*32 + lg*8];
    }

  // epilogue A
  #pragma unroll
  for (int n=0;n<2;n++){
    int ol = n*16 + lr;
    float bgv = b_lg[ow + ol];
    #pragma unroll
    for (int mi=0;mi<4;mi++){
      int r0 = mi*16 + lg*4;
      float u0 = acc1[mi][n][0] * sigm(acc2[mi][n][0] + bgv) * mask_s[r0+0];
      float u1 = acc1[mi][n][1] * sigm(acc2[mi][n][1] + bgv) * mask_s[r0+1];
      float u2 = acc1[mi][n][2] * sigm(acc2[mi][n][2] + bgv) * mask_s[r0+2];
      float u3 = acc1[mi][n][3] * sigm(acc2[mi][n][3] + bgv) * mask_s[r0+3];
      int chunk = (mi*2 + (lg>>1)) ^ (ol & 7);
      *(uint2*)&stg[w][ol*64 + (chunk<<3) + (lg&1)*4] = make_uint2(cvtpk(u0,u1), cvtpk(u2,u3));
    }
  }
  {
    int ol = lane >> 1, rh = lane & 1;
    uint4 pf[4];
    #pragma unroll
    for (int qq=0;qq<4;qq++){
      int m = (rh*4 + qq) ^ (ol & 7);
      pf[qq] = *(const uint4*)&stg[w][ol*64 + (m<<3)];
    }
    uint4* dst = (uint4*)(left_t + tile_off + (ow + ol)*64 + rh*32);
    #pragma unroll
    for (int qq=0;qq<4;qq++) dst[qq] = pf[qq];
  }

  // pass B
  #pragma unroll
  for (int mi=0;mi<4;mi++){ acc1[mi][0]=zero4; acc1[mi][1]=zero4; acc2[mi][0]=zero4; acc2[mi][1]=zero4; }
  #pragma unroll
  for (int kk=0;kk<4;kk++){
    bf16x8 a[4];
    #pragma unroll
    for (int mi=0;mi<4;mi++)
      a[mi] = *(const bf16x8*)&zn[mi*16 + lr][kk*32 + lg*8];
    #pragma unroll
    for (int n=0;n<2;n++)
      #pragma unroll
      for (int mi=0;mi<4;mi++){
        acc1[mi][n] = __builtin_amdgcn_mfma_f32_16x16x32_bf16(a[mi], wl2[kk*2+n], acc1[mi][n], 0,0,0);
        acc2[mi][n] = __builtin_amdgcn_mfma_f32_16x16x32_bf16(a[mi], wg2[kk*2+n], acc2[mi][n], 0,0,0);
      }
  }
  // epilogue B
  #pragma unroll
  for (int n=0;n<2;n++){
    int ol = n*16 + lr;
    float bgv = b_rg[ow + ol];
    #pragma unroll
    for (int mi=0;mi<4;mi++){
      int r0 = mi*16 + lg*4;
      float u0 = acc1[mi][n][0] * sigm(acc2[mi][n][0] + bgv) * mask_s[r0+0];
      float u1 = acc1[mi][n][1] * sigm(acc2[mi][n][1] + bgv) * mask_s[r0+1];
      float u2 = acc1[mi][n][2] * sigm(acc2[mi][n][2] + bgv) * mask_s[r0+2];
      float u3 = acc1[mi][n][3] * sigm(acc2[mi][n][3] + bgv) * mask_s[r0+3];
      int chunk = (mi*2 + (lg>>1)) ^ (ol & 7);
      *(uint2*)&stg[w][ol*64 + (chunk<<3) + (lg&1)*4] = make_uint2(cvtpk(u0,u1), cvtpk(u2,u3));
    }
  }
  {
    int ol = lane >> 1, rh = lane & 1;
    uint4 pf[4];
    #pragma unroll
    for (int qq=0;qq<4;qq++){
      int m = (rh*4 + qq) ^ (ol & 7);
      pf[qq] = *(const uint4*)&stg[w][ol*64 + (m<<3)];
    }
    uint4* dst = (uint4*)(right_t + tile_off + (ow + ol)*64 + rh*32);
    #pragma unroll
    for (int qq=0;qq<4;qq++) dst[qq] = pf[qq];
  }
}

// ------------- k2: per-channel 128x128x512 GEMM, BK=32, gll + XCD swizzle -
__global__ __launch_bounds__(256) void k2_einsum(
    const u16* __restrict__ left_t, const u16* __restrict__ right_t,
    u16* __restrict__ upd16)
{
  __shared__ __align__(16) u16 lds_raw[16384];  // 32 KB
  const int t = threadIdx.x;
  const int lane = t & 63, w = t >> 6;
  const int wi = w >> 1, wj = w & 1;            // wave quadrant: 64x64 out
  const int lr = lane & 15, lg = lane >> 4;

  // XCD-aware bijective swizzle (nwg = 2048, 2048 % 8 == 0; 256/XCD chunk)
  const int lin = (int)(blockIdx.x + (blockIdx.y << 2) + (blockIdx.z << 4));
  const int logical = ((lin & 7) << 8) + (lin >> 3);
  const int c  = logical >> 4;                  // 16 tiles per channel
  const int tl = logical & 15;
  const int i0 = (tl & 3) * 128, j0 = (tl >> 2) * 128;

  f32x4 acc[4][4];
  const f32x4 zero4 = {0.f,0.f,0.f,0.f};
  #pragma unroll
  for (int mi=0;mi<4;mi++)
    #pragma unroll
    for (int nj=0;nj<4;nj++) acc[mi][nj] = zero4;

  auto stage = [&](int buf, int kt){
    size_t kb = (size_t)(kt >> 1)*8192 + (size_t)c*64 + (size_t)((kt & 1)*32);
    #pragma unroll
    for (int q=0;q<2;q++){
      int d   = q*256 + t;
      int row = d >> 2, sl = d & 3;
      int gs  = sl ^ ((row ^ (row >> 2)) & 3);
      const u16* gl = &left_t [(size_t)(i0+row)*65536 + kb + gs*8];
      const u16* gr = &right_t[(size_t)(j0+row)*65536 + kb + gs*8];
      gll16(gl, lds_raw +        buf*4096 + d*8);   // dest linear in lane
      gll16(gr, lds_raw + 8192 + buf*4096 + d*8);
    }
  };

  stage(0, 0);
  __syncthreads();

  for (int kt=0; kt<16; kt++){
    const int buf = kt & 1;
    if (kt < 15) stage(buf^1, kt+1);
    bf16x8 af[4], bfr[4];
    #pragma unroll
    for (int mi=0;mi<4;mi++){
      int row = wi*64 + mi*16 + lr;
      int sw  = (row ^ (row >> 2)) & 3;
      af[mi] = *(const bf16x8*)&lds_raw[buf*4096 + row*32 + ((lg ^ sw)*8)];
    }
    #pragma unroll
    for (int nj=0;nj<4;nj++){
      int row = wj*64 + nj*16 + lr;
      int sw  = (row ^ (row >> 2)) & 3;
      bfr[nj] = *(const bf16x8*)&lds_raw[8192 + buf*4096 + row*32 + ((lg ^ sw)*8)];
    }
    #pragma unroll
    for (int mi=0;mi<4;mi++)
      #pragma unroll
      for (int nj=0;nj<4;nj++)
        acc[mi][nj] = __builtin_amdgcn_mfma_f32_16x16x32_bf16(af[mi], bfr[nj], acc[mi][nj], 0,0,0);
    __syncthreads();
  }

  const float scale = 0.044194173824159216f;   // 1/sqrt(512)
  u16* st = lds_raw;
  #pragma unroll
  for (int half=0; half<2; half++){
    if (wi == half){
      #pragma unroll
      for (int mi=0;mi<4;mi++){
        #pragma unroll
        for (int nj=0;nj<4;nj++){
          int cj = wj*64 + nj*16 + lr;
          #pragma unroll
          for (int g2=0;g2<4;g2++){
            int rl = mi*16 + lg*4 + g2;     // 0..63 within half
            st[rl*136 + cj] = f2bf(acc[mi][nj][g2] * scale);
          }
        }
      }
    }
    __syncthreads();
    {
      int rl = t >> 2, qq = t & 3;
      const uint4* src = (const uint4*)&st[rl*136 + qq*32];
      uint4* dst = (uint4*)(upd16 + (size_t)c*NN
                            + (size_t)(i0 + half*64 + rl)*NSEQ + j0 + qq*32);
      dst[0] = src[0]; dst[1] = src[1]; dst[2] = src[2]; dst[3] = src[3];
    }
    __syncthreads();
  }
}

// ------------- k3a: LN over c of upd16 [c][i*512+j] -> znu [row][c] bf16 --
__global__ __launch_bounds__(256) void k3a_ln(
    const u16* __restrict__ upd16, const float* __restrict__ onw,
    const float* __restrict__ onb, u16* __restrict__ znu)
{
  __shared__ float u[128*129];
  __shared__ float onw_s[128], onb_s[128];
  const int t = threadIdx.x;
  const int i = blockIdx.x;
  const int j0 = blockIdx.y * 128;

  if (t < 32)      ((float4*)onw_s)[t]    = ((const float4*)onw)[t];
  else if (t < 64) ((float4*)onb_s)[t-32] = ((const float4*)onb)[t-32];

  {
    int cr = t >> 1, h = t & 1;
    const uint4* src = (const uint4*)(upd16 + (size_t)cr*NN + (size_t)i*NSEQ + j0 + h*64);
    float* dst = &u[cr*129 + h*64];
    #pragma unroll
    for (int e=0;e<8;e++){
      uint4 v = src[e];
      const u16* hp = (const u16*)&v;
      #pragma unroll
      for (int p=0;p<8;p++) dst[e*8+p] = bf2f(hp[p]);
    }
  }
  __syncthreads();

  int j = t >> 1, h = t & 1;
  float s = 0.f, sq = 0.f;
  #pragma unroll
  for (int e=0;e<64;e++){
    float v = u[(h*64+e)*129 + j];
    s += v; sq += v*v;
  }
  s += __shfl_xor(s,1); sq += __shfl_xor(sq,1);
  float mu = s * (1.f/128.f);
  float rstd = __builtin_amdgcn_rsqf(sq * (1.f/128.f) - mu*mu + 1e-5f);

  uint32_t pk[32];
  #pragma unroll
  for (int e=0;e<64;e+=2){
    int c0 = h*64 + e;
    float v0 = (u[c0*129 + j]     - mu)*rstd*onw_s[c0]   + onb_s[c0];
    float v1 = (u[(c0+1)*129 + j] - mu)*rstd*onw_s[c0+1] + onb_s[c0+1];
    pk[e>>1] = cvtpk(v0, v1);
  }
  uint4* dst = (uint4*)(znu + ((size_t)i*NSEQ + j0 + j)*CH + h*64);
  #pragma unroll
  for (int e=0;e<8;e++) dst[e] = make_uint4(pk[e*4], pk[e*4+1], pk[e*4+2], pk[e*4+3]);
}

// ------------- k3b: out = (LN'd-update @ W_out^T) * sigm(zn@W_og^T+b) * mask
__global__ __launch_bounds__(256) void k3b_out(
    const u16* __restrict__ znu, const u16* __restrict__ znS,
    const float* __restrict__ pmask, const float* __restrict__ b_og,
    const u16* __restrict__ wts, float* __restrict__ out)
{
  __shared__ __align__(16) u16 uL[64][136];
  __shared__ __align__(16) u16 zL[64][136];
  __shared__ float mask_s[64];
  const int t = threadIdx.x;
  const int row0 = blockIdx.x * 64;

  #pragma unroll
  for (int k=0;k<4;k++){
    uint4 vu = *(const uint4*)(znu + (size_t)row0*CH + k*2048 + t*8);
    uint4 vz = *(const uint4*)(znS + (size_t)row0*CH + k*2048 + t*8);
    int r = k*16 + (t>>4), g = t & 15;
    *(uint4*)&uL[r][g*8] = vu;
    *(uint4*)&zL[r][g*8] = vz;
  }
  if (t < 16) ((float4*)mask_s)[t] = ((const float4*)(pmask + row0))[t];
  __syncthreads();

  const int lane = t & 63, w = t >> 6;
  const int lr = lane & 15, lg = lane >> 4;

  f32x4 acc_o[4][2], acc_g[4][2];
  const f32x4 zero4 = {0.f,0.f,0.f,0.f};
  #pragma unroll
  for (int mi=0;mi<4;mi++){ acc_o[mi][0]=zero4; acc_o[mi][1]=zero4; acc_g[mi][0]=zero4; acc_g[mi][1]=zero4; }

  #pragma unroll
  for (int kk=0;kk<4;kk++){
    bf16x8 a[4];
    #pragma unroll
    for (int mi=0;mi<4;mi++)
      a[mi] = *(const bf16x8*)&uL[mi*16 + lr][kk*32 + lg*8];
    #pragma unroll
    for (int n=0;n<2;n++){
      int o = w*32 + n*16 + lr;
      bf16x8 b = *(const bf16x8*)&wts[5*16384 + o*128 + kk*32 + lg*8];
      #pragma unroll
      for (int mi=0;mi<4;mi++)
        acc_o[mi][n] = __builtin_amdgcn_mfma_f32_16x16x32_bf16(a[mi], b, acc_o[mi][n], 0,0,0);
    }
  }
  #pragma unroll
  for (int kk=0;kk<4;kk++){
    bf16x8 a[4];
    #pragma unroll
    for (int mi=0;mi<4;mi++)
      a[mi] = *(const bf16x8*)&zL[mi*16 + lr][kk*32 + lg*8];
    #pragma unroll
    for (int n=0;n<2;n++){
      int o = w*32 + n*16 + lr;
      bf16x8 b = *(const bf16x8*)&wts[4*16384 + o*128 + kk*32 + lg*8];
      #pragma unroll
      for (int mi=0;mi<4;mi++)
        acc_g[mi][n] = __builtin_amdgcn_mfma_f32_16x16x32_bf16(a[mi], b, acc_g[mi][n], 0,0,0);
    }
  }

  #pragma unroll
  for (int n=0;n<2;n++){
    int o = w*32 + n*16 + lr;
    float bgv = b_og[o];
    #pragma unroll
    for (int mi=0;mi<4;mi++){
      #pragma unroll
      for (int g2=0;g2<4;g2++){
        int r = mi*16 + lg*4 + g2;
        float val = acc_o[mi][n][g2] * sigm(acc_g[mi][n][g2] + bgv) * mask_s[r];
        out[(size_t)(row0 + r)*CH + o] = val;
      }
    }
  }
}

// ------------- k3bf: FUSED LN(update) + dual GEMM + gate + store ----------
__global__ __launch_bounds__(256) void k3bf_out(
    const u16* __restrict__ upd16, const u16* __restrict__ znS,
    const float* __restrict__ pmask, const float* __restrict__ onw,
    const float* __restrict__ onb, const float* __restrict__ b_og,
    const u16* __restrict__ wts, float* __restrict__ out)
{
  __shared__ __align__(16) u16 zn[64][136];   // LN'd update (GEMM1 A operand)
  __shared__ __align__(16) u16 zL[64][136];   // znS tile   (GEMM2 A operand)
  __shared__ float ps[4][64], pq[4][64];
  __shared__ float st2[64][2];
  __shared__ float onw_s[128], onb_s[128], mask_s[64];

  const int t = threadIdx.x;
  const int row0 = blockIdx.x * 64;
  const int j  = t & 63;
  const int h2 = t >> 6;

  uint4 vz[4];
  #pragma unroll
  for (int k=0;k<4;k++) vz[k] = *(const uint4*)(znS + (size_t)row0*CH + k*2048 + t*8);

  float v[32];
  #pragma unroll
  for (int e=0;e<32;e++){
    int c = h2*32 + e;
    v[e] = bf2f(upd16[(size_t)c*NN + row0 + j]);
  }

  if (t < 32)      ((float4*)onw_s)[t]     = ((const float4*)onw)[t];
  else if (t < 64) ((float4*)onb_s)[t-32]  = ((const float4*)onb)[t-32];
  else if (t < 80) ((float4*)mask_s)[t-64] = ((const float4*)(pmask + row0))[t-64];

  #pragma unroll
  for (int k=0;k<4;k++){
    int r = k*16 + (t>>4), g = t & 15;
    *(uint4*)&zL[r][g*8] = vz[k];
  }

  {
    float s = 0.f, sq = 0.f;
    #pragma unroll
    for (int e=0;e<32;e++){ s += v[e]; sq += v[e]*v[e]; }
    ps[h2][j] = s; pq[h2][j] = sq;
  }
  __syncthreads();
  if (t < 64){
    float s  = ps[0][t]+ps[1][t]+ps[2][t]+ps[3][t];
    float sq = pq[0][t]+pq[1][t]+pq[2][t]+pq[3][t];
    float mu = s * (1.f/128.f);
    float rstd = __builtin_amdgcn_rsqf(sq * (1.f/128.f) - mu*mu + 1e-5f);
    st2[t][0] = mu; st2[t][1] = rstd;
  }
  __syncthreads();

  {
    float mu = st2[j][0], rstd = st2[j][1];
    #pragma unroll
    for (int q=0;q<4;q++){
      uint32_t pk[4];
      #pragma unroll
      for (int p=0;p<4;p++){
        int e = q*8 + p*2;
        int c = h2*32 + e;
        float y0 = (v[e]   - mu)*rstd*onw_s[c]   + onb_s[c];
        float y1 = (v[e+1] - mu)*rstd*onw_s[c+1] + onb_s[c+1];
        pk[p] = cvtpk(y0, y1);
      }
      *(uint4*)&zn[j][h2*32 + q*8] = make_uint4(pk[0],pk[1],pk[2],pk[3]);
    }
  }
  __syncthreads();

  const int lane = t & 63, w = t >> 6;
  const int lr = lane & 15, lg = lane >> 4;

  f32x4 acc_o[4][2], acc_g[4][2];
  const f32x4 zero4 = {0.f,0.f,0.f,0.f};
  #pragma unroll
  for (int mi=0;mi<4;mi++){ acc_o[mi][0]=zero4; acc_o[mi][1]=zero4; acc_g[mi][0]=zero4; acc_g[mi][1]=zero4; }

  #pragma unroll
  for (int kk=0;kk<4;kk++){
    bf16x8 a[4];
    #pragma unroll
    for (int mi=0;mi<4;mi++)
      a[mi] = *(const bf16x8*)&zn[mi*16 + lr][kk*32 + lg*8];
    #pragma unroll
    for (int n=0;n<2;n++){
      int o = w*32 + n*16 + lr;
      bf16x8 b = *(const bf16x8*)&wts[5*16384 + o*128 + kk*32 + lg*8];
      #pragma unroll
      for (int mi=0;mi<4;mi++)
        acc_o[mi][n] = __builtin_amdgcn_mfma_f32_16x16x32_bf16(a[mi], b, acc_o[mi][n], 0,0,0);
    }
  }
  #pragma unroll
  for (int kk=0;kk<4;kk++){
    bf16x8 a[4];
    #pragma unroll
    for (int mi=0;mi<4;mi++)
      a[mi] = *(const bf16x8*)&zL[mi*16 + lr][kk*32 + lg*8];
    #pragma unroll
    for (int n=0;n<2;n++){
      int o = w*32 + n*16 + lr;
      bf16x8 b = *(const bf16x8*)&wts[4*16384 + o*128 + kk*32 + lg*8];
      #pragma unroll
      for (int mi=0;mi<4;mi++)
        acc_g[mi][n] = __builtin_amdgcn_mfma_f32_16x16x32_bf16(a[mi], b, acc_g[mi][n], 0,0,0);
    }
  }

  #pragma unroll
  for (int n=0;n<2;n++){
    int o = w*32 + n*16 + lr;
    float bgv = b_og[o];
    #pragma unroll
    for (int mi=0;mi<4;mi++){
      #pragma unroll
      for (int g2=0;g2<4;g2++){
        int r = mi*16 + lg*4 + g2;
        float val = acc_o[mi][n][g2] * sigm(acc_g[mi][n][g2] + bgv) * mask_s[r];
        out[(size_t)(row0 + r)*CH + o] = val;
      }
    }
  }
}

// --------------------------- launcher ------------------------------------
extern "C" void kernel_launch(void* const* d_in, const int* in_sizes, int n_in,
                              void* d_out, int out_size, void* d_ws, size_t ws_size,
                              hipStream_t stream)
{
  const float* z       = (const float*)d_in[0];
  const float* pmask   = (const float*)d_in[1];
  const float* lnw     = (const float*)d_in[2];
  const float* lnb     = (const float*)d_in[3];
  const float* W_left  = (const float*)d_in[4];
  const float* W_right = (const float*)d_in[5];
  const float* W_lgate = (const float*)d_in[6];
  const float* b_lgate = (const float*)d_in[7];
  const float* W_rgate = (const float*)d_in[8];
  const float* b_rgate = (const float*)d_in[9];
  const float* onw     = (const float*)d_in[10];
  const float* onb     = (const float*)d_in[11];
  const float* W_out   = (const float*)d_in[12];
  const float* W_ogate = (const float*)d_in[13];
  const float* b_ogate = (const float*)d_in[14];

  const size_t SLOT = 67108864;   // 64 MiB
  uint8_t* ws = (uint8_t*)d_ws;
  u16* left_t  = (u16*)(ws);
  u16* right_t = (u16*)(ws + SLOT);
  u16* znS     = (u16*)(ws + 2*SLOT);

  const bool fused = (ws_size >= 4*SLOT + 196608);
  u16* wts   = (u16*)(ws + (fused ? 4*SLOT : 3*SLOT));
  u16* upd16 = fused ? (u16*)(ws + 3*SLOT) : (u16*)d_out;

  k0_cvt<<<96, 256, 0, stream>>>(W_left, W_lgate, W_right, W_rgate, W_ogate, W_out, wts);
  k1ab_proj<<<4096, 256, 0, stream>>>(z, pmask, lnw, lnb, b_lgate, b_rgate, wts,
                                      znS, left_t, right_t);
  k2_einsum<<<dim3(4,4,128), 256, 0, stream>>>(left_t, right_t, upd16);

  if (fused){
    k3bf_out<<<4096, 256, 0, stream>>>(upd16, znS, pmask, onw, onb, b_ogate, wts,
                                       (float*)d_out);
  } else {
    k3a_ln<<<dim3(512,4), 256, 0, stream>>>(upd16, onw, onb, left_t /*znu*/);
    k3b_out<<<4096, 256, 0, stream>>>(left_t /*znu*/, znS, pmask, b_ogate, wts,
                                      (float*)d_out);
  }
}

// Round 15
// 278.117 us; speedup vs baseline: 1.1165x; 1.1165x over previous
//
#include <hip/hip_runtime.h>
#include <stdint.h>

#define NSEQ 512
#define CH   128
#define NN   (NSEQ*NSEQ)   // 262144

typedef unsigned short u16;
typedef __attribute__((ext_vector_type(8))) short bf16x8;  // 8 bf16 = 4 VGPRs
typedef __attribute__((ext_vector_type(4))) float f32x4;

__device__ __forceinline__ u16 f2bf(float x){          // RNE
  uint32_t u = __float_as_uint(x);
  u += 0x7fffu + ((u >> 16) & 1u);
  return (u16)(u >> 16);
}
__device__ __forceinline__ float bf2f(u16 h){
  return __uint_as_float(((uint32_t)h) << 16);
}
__device__ __forceinline__ uint32_t cvtpk(float lo, float hi){  // bf16(lo)|bf16(hi)<<16
  uint32_t r;
  asm volatile("v_cvt_pk_bf16_f32 %0, %1, %2" : "=v"(r) : "v"(lo), "v"(hi));
  return r;
}
__device__ __forceinline__ float sigm(float x){
  return __builtin_amdgcn_rcpf(1.0f + __expf(-x));
}
__device__ __forceinline__ void gll16(const void* g, void* l){  // 16B global->LDS DMA
  __builtin_amdgcn_global_load_lds((const __attribute__((address_space(1))) void*)g,
                                   (__attribute__((address_space(3))) void*)l, 16, 0, 0);
}

// left/right tensor layout: [i (512)][kblk (8)][c (128)][kin (64)] u16
// offset = i*65536 + kblk*8192 + c*64 + kin   (flat row n = i*512 + kblk*64 + kin)

// ------------- k0: cast 6 weight matrices fp32 -> bf16 -------------
// slot order: 0=W_left 1=W_lgate 2=W_right 3=W_rgate 4=W_ogate 5=W_out
__global__ void k0_cvt(const float* __restrict__ w0, const float* __restrict__ w1,
                       const float* __restrict__ w2, const float* __restrict__ w3,
                       const float* __restrict__ w4, const float* __restrict__ w5,
                       u16* __restrict__ out)
{
  int mat = blockIdx.x >> 4;
  int blk = blockIdx.x & 15;
  const float* src = (mat==0)?w0:(mat==1)?w1:(mat==2)?w2:(mat==3)?w3:(mat==4)?w4:w5;
  int idx = (blk*256 + (int)threadIdx.x) * 4;
  float4 v = *(const float4*)(src + idx);
  uint2 pk;
  pk.x = cvtpk(v.x, v.y);
  pk.y = cvtpk(v.z, v.w);
  *(uint2*)(out + mat*16384 + idx) = pk;
}

// ------------- k1ab: FUSED LN(z) + 2 gated projections, 128 rows/block ----
// PASS-MAJOR order: each pass's weight fragments loaded ONCE, used by both
// row-tiles (halves weight L2 traffic + weight-wait events vs tile-major).
__global__ __launch_bounds__(256) void k1ab_proj(
    const float* __restrict__ z, const float* __restrict__ pmask,
    const float* __restrict__ lnw, const float* __restrict__ lnb,
    const float* __restrict__ b_lg, const float* __restrict__ b_rg,
    const u16* __restrict__ wts, u16* __restrict__ znS,
    u16* __restrict__ left_t, u16* __restrict__ right_t)
{
  __shared__ __align__(16) u16 zn[2][64][136];  // 34 KB
  __shared__ __align__(16) u16 stg[4][2048];    // 16 KB (per-wave stage)
  __shared__ float lnw_s[128], lnb_s[128], mask_s[128];
  const int t = threadIdx.x;
  const int row0 = blockIdx.x * 128;

  if (t < 32)      ((float4*)lnw_s)[t]     = ((const float4*)lnw)[t];
  else if (t < 64) ((float4*)lnb_s)[t-32]  = ((const float4*)lnb)[t-32];
  else if (t < 96) ((float4*)mask_s)[t-64] = ((const float4*)(pmask + row0))[t-64];

  // lane-contiguous z loads: tile0 = float4 idx e*256+t, tile1 = +2048
  const float4* zt = (const float4*)(z + (size_t)row0 * CH);
  float4 v0[8], v1[8];
  #pragma unroll
  for (int e=0;e<8;e++) v0[e] = zt[e*256 + t];
  #pragma unroll
  for (int e=0;e<8;e++) v1[e] = zt[2048 + e*256 + t];
  __syncthreads();   // lnw_s/lnb_s/mask_s visible

  const int rsub = t >> 5;          // row sub-index within step
  const int c4   = (t & 31) * 4;    // this thread's 4 channels

  // ----- LN tile 0: per step e, row = e*8+rsub; stats over 32-lane half -----
  #pragma unroll
  for (int e=0;e<8;e++){
    float4 vv = v0[e];
    float s  = vv.x + vv.y + vv.z + vv.w;
    float sq = vv.x*vv.x + vv.y*vv.y + vv.z*vv.z + vv.w*vv.w;
    s += __shfl_xor(s,1);  sq += __shfl_xor(sq,1);
    s += __shfl_xor(s,2);  sq += __shfl_xor(sq,2);
    s += __shfl_xor(s,4);  sq += __shfl_xor(sq,4);
    s += __shfl_xor(s,8);  sq += __shfl_xor(sq,8);
    s += __shfl_xor(s,16); sq += __shfl_xor(sq,16);
    float mu = s * (1.f/128.f);
    float rstd = __builtin_amdgcn_rsqf(sq * (1.f/128.f) - mu*mu + 1e-5f);
    float y0 = (vv.x - mu)*rstd*lnw_s[c4+0] + lnb_s[c4+0];
    float y1 = (vv.y - mu)*rstd*lnw_s[c4+1] + lnb_s[c4+1];
    float y2 = (vv.z - mu)*rstd*lnw_s[c4+2] + lnb_s[c4+2];
    float y3 = (vv.w - mu)*rstd*lnw_s[c4+3] + lnb_s[c4+3];
    uint2 pk = make_uint2(cvtpk(y0,y1), cvtpk(y2,y3));
    ((uint2*)(znS + (size_t)row0*CH))[e*256 + t] = pk;   // coalesced 8B/lane
    int row = e*8 + rsub;
    *(uint2*)&zn[0][row][c4] = pk;
  }
  // ----- LN tile 1 -----
  #pragma unroll
  for (int e=0;e<8;e++){
    float4 vv = v1[e];
    float s  = vv.x + vv.y + vv.z + vv.w;
    float sq = vv.x*vv.x + vv.y*vv.y + vv.z*vv.z + vv.w*vv.w;
    s += __shfl_xor(s,1);  sq += __shfl_xor(sq,1);
    s += __shfl_xor(s,2);  sq += __shfl_xor(sq,2);
    s += __shfl_xor(s,4);  sq += __shfl_xor(sq,4);
    s += __shfl_xor(s,8);  sq += __shfl_xor(sq,8);
    s += __shfl_xor(s,16); sq += __shfl_xor(sq,16);
    float mu = s * (1.f/128.f);
    float rstd = __builtin_amdgcn_rsqf(sq * (1.f/128.f) - mu*mu + 1e-5f);
    float y0 = (vv.x - mu)*rstd*lnw_s[c4+0] + lnb_s[c4+0];
    float y1 = (vv.y - mu)*rstd*lnw_s[c4+1] + lnb_s[c4+1];
    float y2 = (vv.z - mu)*rstd*lnw_s[c4+2] + lnb_s[c4+2];
    float y3 = (vv.w - mu)*rstd*lnw_s[c4+3] + lnb_s[c4+3];
    uint2 pk = make_uint2(cvtpk(y0,y1), cvtpk(y2,y3));
    ((uint2*)(znS + (size_t)(row0+64)*CH))[e*256 + t] = pk;
    int row = e*8 + rsub;
    *(uint2*)&zn[1][row][c4] = pk;
  }
  __syncthreads();   // zn ready

  const int lane = t & 63;
  const int w = t >> 6;
  const int lr = lane & 15;
  const int lg = lane >> 4;
  const int ow = w*32;
  const f32x4 zero4 = {0.f,0.f,0.f,0.f};

  // ================= PASS A (left + lgate): weights loaded once ===========
  {
    bf16x8 wl[8], wg[8];
    #pragma unroll
    for (int kk=0;kk<4;kk++)
      #pragma unroll
      for (int n=0;n<2;n++){
        int o = ow + n*16 + lr;
        wl[kk*2+n] = *(const bf16x8*)&wts[0*16384 + o*128 + kk*32 + lg*8];
        wg[kk*2+n] = *(const bf16x8*)&wts[1*16384 + o*128 + kk*32 + lg*8];
      }

    #pragma unroll
    for (int tt=0; tt<2; tt++){
      const int r0t = row0 + tt*64;
      const size_t tile_off = (size_t)(r0t >> 9)*65536 + (size_t)((r0t >> 6) & 7)*8192;
      const float* msk = mask_s + tt*64;

      f32x4 acc1[4][2], acc2[4][2];
      #pragma unroll
      for (int mi=0;mi<4;mi++){ acc1[mi][0]=zero4; acc1[mi][1]=zero4; acc2[mi][0]=zero4; acc2[mi][1]=zero4; }
      #pragma unroll
      for (int kk=0;kk<4;kk++){
        bf16x8 a[4];
        #pragma unroll
        for (int mi=0;mi<4;mi++)
          a[mi] = *(const bf16x8*)&zn[tt][mi*16 + lr][kk*32 + lg*8];
        #pragma unroll
        for (int n=0;n<2;n++)
          #pragma unroll
          for (int mi=0;mi<4;mi++){
            acc1[mi][n] = __builtin_amdgcn_mfma_f32_16x16x32_bf16(a[mi], wl[kk*2+n], acc1[mi][n], 0,0,0);
            acc2[mi][n] = __builtin_amdgcn_mfma_f32_16x16x32_bf16(a[mi], wg[kk*2+n], acc2[mi][n], 0,0,0);
          }
      }
      #pragma unroll
      for (int n=0;n<2;n++){
        int ol = n*16 + lr;
        float bgv = b_lg[ow + ol];
        #pragma unroll
        for (int mi=0;mi<4;mi++){
          int r0 = mi*16 + lg*4;
          float u0 = acc1[mi][n][0] * sigm(acc2[mi][n][0] + bgv) * msk[r0+0];
          float u1 = acc1[mi][n][1] * sigm(acc2[mi][n][1] + bgv) * msk[r0+1];
          float u2 = acc1[mi][n][2] * sigm(acc2[mi][n][2] + bgv) * msk[r0+2];
          float u3 = acc1[mi][n][3] * sigm(acc2[mi][n][3] + bgv) * msk[r0+3];
          int chunk = (mi*2 + (lg>>1)) ^ (ol & 7);
          *(uint2*)&stg[w][ol*64 + (chunk<<3) + (lg&1)*4] = make_uint2(cvtpk(u0,u1), cvtpk(u2,u3));
        }
      }
      {
        int ol = lane >> 1, rh = lane & 1;
        uint4 pf[4];
        #pragma unroll
        for (int qq=0;qq<4;qq++){
          int m = (rh*4 + qq) ^ (ol & 7);
          pf[qq] = *(const uint4*)&stg[w][ol*64 + (m<<3)];
        }
        uint4* dst = (uint4*)(left_t + tile_off + (ow + ol)*64 + rh*32);
        #pragma unroll
        for (int qq=0;qq<4;qq++) dst[qq] = pf[qq];
      }
    }
  }

  // ================= PASS B (right + rgate): weights loaded once ==========
  {
    bf16x8 wl2[8], wg2[8];
    #pragma unroll
    for (int kk=0;kk<4;kk++)
      #pragma unroll
      for (int n=0;n<2;n++){
        int o = ow + n*16 + lr;
        wl2[kk*2+n] = *(const bf16x8*)&wts[2*16384 + o*128 + kk*32 + lg*8];
        wg2[kk*2+n] = *(const bf16x8*)&wts[3*16384 + o*128 + kk*32 + lg*8];
      }

    #pragma unroll
    for (int tt=0; tt<2; tt++){
      const int r0t = row0 + tt*64;
      const size_t tile_off = (size_t)(r0t >> 9)*65536 + (size_t)((r0t >> 6) & 7)*8192;
      const float* msk = mask_s + tt*64;

      f32x4 acc1[4][2], acc2[4][2];
      #pragma unroll
      for (int mi=0;mi<4;mi++){ acc1[mi][0]=zero4; acc1[mi][1]=zero4; acc2[mi][0]=zero4; acc2[mi][1]=zero4; }
      #pragma unroll
      for (int kk=0;kk<4;kk++){
        bf16x8 a[4];
        #pragma unroll
        for (int mi=0;mi<4;mi++)
          a[mi] = *(const bf16x8*)&zn[tt][mi*16 + lr][kk*32 + lg*8];
        #pragma unroll
        for (int n=0;n<2;n++)
          #pragma unroll
          for (int mi=0;mi<4;mi++){
            acc1[mi][n] = __builtin_amdgcn_mfma_f32_16x16x32_bf16(a[mi], wl2[kk*2+n], acc1[mi][n], 0,0,0);
            acc2[mi][n] = __builtin_amdgcn_mfma_f32_16x16x32_bf16(a[mi], wg2[kk*2+n], acc2[mi][n], 0,0,0);
          }
      }
      #pragma unroll
      for (int n=0;n<2;n++){
        int ol = n*16 + lr;
        float bgv = b_rg[ow + ol];
        #pragma unroll
        for (int mi=0;mi<4;mi++){
          int r0 = mi*16 + lg*4;
          float u0 = acc1[mi][n][0] * sigm(acc2[mi][n][0] + bgv) * msk[r0+0];
          float u1 = acc1[mi][n][1] * sigm(acc2[mi][n][1] + bgv) * msk[r0+1];
          float u2 = acc1[mi][n][2] * sigm(acc2[mi][n][2] + bgv) * msk[r0+2];
          float u3 = acc1[mi][n][3] * sigm(acc2[mi][n][3] + bgv) * msk[r0+3];
          int chunk = (mi*2 + (lg>>1)) ^ (ol & 7);
          *(uint2*)&stg[w][ol*64 + (chunk<<3) + (lg&1)*4] = make_uint2(cvtpk(u0,u1), cvtpk(u2,u3));
        }
      }
      {
        int ol = lane >> 1, rh = lane & 1;
        uint4 pf[4];
        #pragma unroll
        for (int qq=0;qq<4;qq++){
          int m = (rh*4 + qq) ^ (ol & 7);
          pf[qq] = *(const uint4*)&stg[w][ol*64 + (m<<3)];
        }
        uint4* dst = (uint4*)(right_t + tile_off + (ow + ol)*64 + rh*32);
        #pragma unroll
        for (int qq=0;qq<4;qq++) dst[qq] = pf[qq];
      }
    }
  }
}

// ------------- k2: per-channel 128x128x512 GEMM, BK=32, gll + XCD swizzle -
__global__ __launch_bounds__(256) void k2_einsum(
    const u16* __restrict__ left_t, const u16* __restrict__ right_t,
    u16* __restrict__ upd16)
{
  __shared__ __align__(16) u16 lds_raw[16384];  // 32 KB
  const int t = threadIdx.x;
  const int lane = t & 63, w = t >> 6;
  const int wi = w >> 1, wj = w & 1;            // wave quadrant: 64x64 out
  const int lr = lane & 15, lg = lane >> 4;

  // XCD-aware bijective swizzle (nwg = 2048, 2048 % 8 == 0; 256/XCD chunk)
  const int lin = (int)(blockIdx.x + (blockIdx.y << 2) + (blockIdx.z << 4));
  const int logical = ((lin & 7) << 8) + (lin >> 3);
  const int c  = logical >> 4;                  // 16 tiles per channel
  const int tl = logical & 15;
  const int i0 = (tl & 3) * 128, j0 = (tl >> 2) * 128;

  f32x4 acc[4][4];
  const f32x4 zero4 = {0.f,0.f,0.f,0.f};
  #pragma unroll
  for (int mi=0;mi<4;mi++)
    #pragma unroll
    for (int nj=0;nj<4;nj++) acc[mi][nj] = zero4;

  auto stage = [&](int buf, int kt){
    size_t kb = (size_t)(kt >> 1)*8192 + (size_t)c*64 + (size_t)((kt & 1)*32);
    #pragma unroll
    for (int q=0;q<2;q++){
      int d   = q*256 + t;
      int row = d >> 2, sl = d & 3;
      int gs  = sl ^ ((row ^ (row >> 2)) & 3);
      const u16* gl = &left_t [(size_t)(i0+row)*65536 + kb + gs*8];
      const u16* gr = &right_t[(size_t)(j0+row)*65536 + kb + gs*8];
      gll16(gl, lds_raw +        buf*4096 + d*8);   // dest linear in lane
      gll16(gr, lds_raw + 8192 + buf*4096 + d*8);
    }
  };

  stage(0, 0);
  __syncthreads();

  for (int kt=0; kt<16; kt++){
    const int buf = kt & 1;
    if (kt < 15) stage(buf^1, kt+1);
    bf16x8 af[4], bfr[4];
    #pragma unroll
    for (int mi=0;mi<4;mi++){
      int row = wi*64 + mi*16 + lr;
      int sw  = (row ^ (row >> 2)) & 3;
      af[mi] = *(const bf16x8*)&lds_raw[buf*4096 + row*32 + ((lg ^ sw)*8)];
    }
    #pragma unroll
    for (int nj=0;nj<4;nj++){
      int row = wj*64 + nj*16 + lr;
      int sw  = (row ^ (row >> 2)) & 3;
      bfr[nj] = *(const bf16x8*)&lds_raw[8192 + buf*4096 + row*32 + ((lg ^ sw)*8)];
    }
    #pragma unroll
    for (int mi=0;mi<4;mi++)
      #pragma unroll
      for (int nj=0;nj<4;nj++)
        acc[mi][nj] = __builtin_amdgcn_mfma_f32_16x16x32_bf16(af[mi], bfr[nj], acc[mi][nj], 0,0,0);
    __syncthreads();
  }

  const float scale = 0.044194173824159216f;   // 1/sqrt(512)
  u16* st = lds_raw;
  #pragma unroll
  for (int half=0; half<2; half++){
    if (wi == half){
      #pragma unroll
      for (int mi=0;mi<4;mi++){
        #pragma unroll
        for (int nj=0;nj<4;nj++){
          int cj = wj*64 + nj*16 + lr;
          #pragma unroll
          for (int g2=0;g2<4;g2++){
            int rl = mi*16 + lg*4 + g2;     // 0..63 within half
            st[rl*136 + cj] = f2bf(acc[mi][nj][g2] * scale);
          }
        }
      }
    }
    __syncthreads();
    {
      int rl = t >> 2, qq = t & 3;
      const uint4* src = (const uint4*)&st[rl*136 + qq*32];
      uint4* dst = (uint4*)(upd16 + (size_t)c*NN
                            + (size_t)(i0 + half*64 + rl)*NSEQ + j0 + qq*32);
      dst[0] = src[0]; dst[1] = src[1]; dst[2] = src[2]; dst[3] = src[3];
    }
    __syncthreads();
  }
}

// ------------- k3a: LN over c of upd16 [c][i*512+j] -> znu [row][c] bf16 --
__global__ __launch_bounds__(256) void k3a_ln(
    const u16* __restrict__ upd16, const float* __restrict__ onw,
    const float* __restrict__ onb, u16* __restrict__ znu)
{
  __shared__ float u[128*129];
  __shared__ float onw_s[128], onb_s[128];
  const int t = threadIdx.x;
  const int i = blockIdx.x;
  const int j0 = blockIdx.y * 128;

  if (t < 32)      ((float4*)onw_s)[t]    = ((const float4*)onw)[t];
  else if (t < 64) ((float4*)onb_s)[t-32] = ((const float4*)onb)[t-32];

  {
    int cr = t >> 1, h = t & 1;
    const uint4* src = (const uint4*)(upd16 + (size_t)cr*NN + (size_t)i*NSEQ + j0 + h*64);
    float* dst = &u[cr*129 + h*64];
    #pragma unroll
    for (int e=0;e<8;e++){
      uint4 v = src[e];
      const u16* hp = (const u16*)&v;
      #pragma unroll
      for (int p=0;p<8;p++) dst[e*8+p] = bf2f(hp[p]);
    }
  }
  __syncthreads();

  int j = t >> 1, h = t & 1;
  float s = 0.f, sq = 0.f;
  #pragma unroll
  for (int e=0;e<64;e++){
    float v = u[(h*64+e)*129 + j];
    s += v; sq += v*v;
  }
  s += __shfl_xor(s,1); sq += __shfl_xor(sq,1);
  float mu = s * (1.f/128.f);
  float rstd = __builtin_amdgcn_rsqf(sq * (1.f/128.f) - mu*mu + 1e-5f);

  uint32_t pk[32];
  #pragma unroll
  for (int e=0;e<64;e+=2){
    int c0 = h*64 + e;
    float v0 = (u[c0*129 + j]     - mu)*rstd*onw_s[c0]   + onb_s[c0];
    float v1 = (u[(c0+1)*129 + j] - mu)*rstd*onw_s[c0+1] + onb_s[c0+1];
    pk[e>>1] = cvtpk(v0, v1);
  }
  uint4* dst = (uint4*)(znu + ((size_t)i*NSEQ + j0 + j)*CH + h*64);
  #pragma unroll
  for (int e=0;e<8;e++) dst[e] = make_uint4(pk[e*4], pk[e*4+1], pk[e*4+2], pk[e*4+3]);
}

// ------------- k3b: out = (LN'd-update @ W_out^T) * sigm(zn@W_og^T+b) * mask
__global__ __launch_bounds__(256) void k3b_out(
    const u16* __restrict__ znu, const u16* __restrict__ znS,
    const float* __restrict__ pmask, const float* __restrict__ b_og,
    const u16* __restrict__ wts, float* __restrict__ out)
{
  __shared__ __align__(16) u16 uL[64][136];
  __shared__ __align__(16) u16 zL[64][136];
  __shared__ float mask_s[64];
  const int t = threadIdx.x;
  const int row0 = blockIdx.x * 64;

  #pragma unroll
  for (int k=0;k<4;k++){
    uint4 vu = *(const uint4*)(znu + (size_t)row0*CH + k*2048 + t*8);
    uint4 vz = *(const uint4*)(znS + (size_t)row0*CH + k*2048 + t*8);
    int r = k*16 + (t>>4), g = t & 15;
    *(uint4*)&uL[r][g*8] = vu;
    *(uint4*)&zL[r][g*8] = vz;
  }
  if (t < 16) ((float4*)mask_s)[t] = ((const float4*)(pmask + row0))[t];
  __syncthreads();

  const int lane = t & 63, w = t >> 6;
  const int lr = lane & 15, lg = lane >> 4;

  f32x4 acc_o[4][2], acc_g[4][2];
  const f32x4 zero4 = {0.f,0.f,0.f,0.f};
  #pragma unroll
  for (int mi=0;mi<4;mi++){ acc_o[mi][0]=zero4; acc_o[mi][1]=zero4; acc_g[mi][0]=zero4; acc_g[mi][1]=zero4; }

  #pragma unroll
  for (int kk=0;kk<4;kk++){
    bf16x8 a[4];
    #pragma unroll
    for (int mi=0;mi<4;mi++)
      a[mi] = *(const bf16x8*)&uL[mi*16 + lr][kk*32 + lg*8];
    #pragma unroll
    for (int n=0;n<2;n++){
      int o = w*32 + n*16 + lr;
      bf16x8 b = *(const bf16x8*)&wts[5*16384 + o*128 + kk*32 + lg*8];
      #pragma unroll
      for (int mi=0;mi<4;mi++)
        acc_o[mi][n] = __builtin_amdgcn_mfma_f32_16x16x32_bf16(a[mi], b, acc_o[mi][n], 0,0,0);
    }
  }
  #pragma unroll
  for (int kk=0;kk<4;kk++){
    bf16x8 a[4];
    #pragma unroll
    for (int mi=0;mi<4;mi++)
      a[mi] = *(const bf16x8*)&zL[mi*16 + lr][kk*32 + lg*8];
    #pragma unroll
    for (int n=0;n<2;n++){
      int o = w*32 + n*16 + lr;
      bf16x8 b = *(const bf16x8*)&wts[4*16384 + o*128 + kk*32 + lg*8];
      #pragma unroll
      for (int mi=0;mi<4;mi++)
        acc_g[mi][n] = __builtin_amdgcn_mfma_f32_16x16x32_bf16(a[mi], b, acc_g[mi][n], 0,0,0);
    }
  }

  #pragma unroll
  for (int n=0;n<2;n++){
    int o = w*32 + n*16 + lr;
    float bgv = b_og[o];
    #pragma unroll
    for (int mi=0;mi<4;mi++){
      #pragma unroll
      for (int g2=0;g2<4;g2++){
        int r = mi*16 + lg*4 + g2;
        float val = acc_o[mi][n][g2] * sigm(acc_g[mi][n][g2] + bgv) * mask_s[r];
        out[(size_t)(row0 + r)*CH + o] = val;
      }
    }
  }
}

// ------------- k3bf: FUSED LN(update) + dual GEMM + gate + store ----------
__global__ __launch_bounds__(256) void k3bf_out(
    const u16* __restrict__ upd16, const u16* __restrict__ znS,
    const float* __restrict__ pmask, const float* __restrict__ onw,
    const float* __restrict__ onb, const float* __restrict__ b_og,
    const u16* __restrict__ wts, float* __restrict__ out)
{
  __shared__ __align__(16) u16 zn[64][136];   // LN'd update (GEMM1 A operand)
  __shared__ __align__(16) u16 zL[64][136];   // znS tile   (GEMM2 A operand)
  __shared__ float ps[4][64], pq[4][64];
  __shared__ float st2[64][2];
  __shared__ float onw_s[128], onb_s[128], mask_s[64];

  const int t = threadIdx.x;
  const int row0 = blockIdx.x * 64;
  const int j  = t & 63;
  const int h2 = t >> 6;

  uint4 vz[4];
  #pragma unroll
  for (int k=0;k<4;k++) vz[k] = *(const uint4*)(znS + (size_t)row0*CH + k*2048 + t*8);

  float v[32];
  #pragma unroll
  for (int e=0;e<32;e++){
    int c = h2*32 + e;
    v[e] = bf2f(upd16[(size_t)c*NN + row0 + j]);
  }

  if (t < 32)      ((float4*)onw_s)[t]     = ((const float4*)onw)[t];
  else if (t < 64) ((float4*)onb_s)[t-32]  = ((const float4*)onb)[t-32];
  else if (t < 80) ((float4*)mask_s)[t-64] = ((const float4*)(pmask + row0))[t-64];

  #pragma unroll
  for (int k=0;k<4;k++){
    int r = k*16 + (t>>4), g = t & 15;
    *(uint4*)&zL[r][g*8] = vz[k];
  }

  {
    float s = 0.f, sq = 0.f;
    #pragma unroll
    for (int e=0;e<32;e++){ s += v[e]; sq += v[e]*v[e]; }
    ps[h2][j] = s; pq[h2][j] = sq;
  }
  __syncthreads();
  if (t < 64){
    float s  = ps[0][t]+ps[1][t]+ps[2][t]+ps[3][t];
    float sq = pq[0][t]+pq[1][t]+pq[2][t]+pq[3][t];
    float mu = s * (1.f/128.f);
    float rstd = __builtin_amdgcn_rsqf(sq * (1.f/128.f) - mu*mu + 1e-5f);
    st2[t][0] = mu; st2[t][1] = rstd;
  }
  __syncthreads();

  {
    float mu = st2[j][0], rstd = st2[j][1];
    #pragma unroll
    for (int q=0;q<4;q++){
      uint32_t pk[4];
      #pragma unroll
      for (int p=0;p<4;p++){
        int e = q*8 + p*2;
        int c = h2*32 + e;
        float y0 = (v[e]   - mu)*rstd*onw_s[c]   + onb_s[c];
        float y1 = (v[e+1] - mu)*rstd*onw_s[c+1] + onb_s[c+1];
        pk[p] = cvtpk(y0, y1);
      }
      *(uint4*)&zn[j][h2*32 + q*8] = make_uint4(pk[0],pk[1],pk[2],pk[3]);
    }
  }
  __syncthreads();

  const int lane = t & 63, w = t >> 6;
  const int lr = lane & 15, lg = lane >> 4;

  f32x4 acc_o[4][2], acc_g[4][2];
  const f32x4 zero4 = {0.f,0.f,0.f,0.f};
  #pragma unroll
  for (int mi=0;mi<4;mi++){ acc_o[mi][0]=zero4; acc_o[mi][1]=zero4; acc_g[mi][0]=zero4; acc_g[mi][1]=zero4; }

  #pragma unroll
  for (int kk=0;kk<4;kk++){
    bf16x8 a[4];
    #pragma unroll
    for (int mi=0;mi<4;mi++)
      a[mi] = *(const bf16x8*)&zn[mi*16 + lr][kk*32 + lg*8];
    #pragma unroll
    for (int n=0;n<2;n++){
      int o = w*32 + n*16 + lr;
      bf16x8 b = *(const bf16x8*)&wts[5*16384 + o*128 + kk*32 + lg*8];
      #pragma unroll
      for (int mi=0;mi<4;mi++)
        acc_o[mi][n] = __builtin_amdgcn_mfma_f32_16x16x32_bf16(a[mi], b, acc_o[mi][n], 0,0,0);
    }
  }
  #pragma unroll
  for (int kk=0;kk<4;kk++){
    bf16x8 a[4];
    #pragma unroll
    for (int mi=0;mi<4;mi++)
      a[mi] = *(const bf16x8*)&zL[mi*16 + lr][kk*32 + lg*8];
    #pragma unroll
    for (int n=0;n<2;n++){
      int o = w*32 + n*16 + lr;
      bf16x8 b = *(const bf16x8*)&wts[4*16384 + o*128 + kk*32 + lg*8];
      #pragma unroll
      for (int mi=0;mi<4;mi++)
        acc_g[mi][n] = __builtin_amdgcn_mfma_f32_16x16x32_bf16(a[mi], b, acc_g[mi][n], 0,0,0);
    }
  }

  #pragma unroll
  for (int n=0;n<2;n++){
    int o = w*32 + n*16 + lr;
    float bgv = b_og[o];
    #pragma unroll
    for (int mi=0;mi<4;mi++){
      #pragma unroll
      for (int g2=0;g2<4;g2++){
        int r = mi*16 + lg*4 + g2;
        float val = acc_o[mi][n][g2] * sigm(acc_g[mi][n][g2] + bgv) * mask_s[r];
        out[(size_t)(row0 + r)*CH + o] = val;
      }
    }
  }
}

// --------------------------- launcher ------------------------------------
extern "C" void kernel_launch(void* const* d_in, const int* in_sizes, int n_in,
                              void* d_out, int out_size, void* d_ws, size_t ws_size,
                              hipStream_t stream)
{
  const float* z       = (const float*)d_in[0];
  const float* pmask   = (const float*)d_in[1];
  const float* lnw     = (const float*)d_in[2];
  const float* lnb     = (const float*)d_in[3];
  const float* W_left  = (const float*)d_in[4];
  const float* W_right = (const float*)d_in[5];
  const float* W_lgate = (const float*)d_in[6];
  const float* b_lgate = (const float*)d_in[7];
  const float* W_rgate = (const float*)d_in[8];
  const float* b_rgate = (const float*)d_in[9];
  const float* onw     = (const float*)d_in[10];
  const float* onb     = (const float*)d_in[11];
  const float* W_out   = (const float*)d_in[12];
  const float* W_ogate = (const float*)d_in[13];
  const float* b_ogate = (const float*)d_in[14];

  const size_t SLOT = 67108864;   // 64 MiB
  uint8_t* ws = (uint8_t*)d_ws;
  u16* left_t  = (u16*)(ws);
  u16* right_t = (u16*)(ws + SLOT);
  u16* znS     = (u16*)(ws + 2*SLOT);

  const bool fused = (ws_size >= 4*SLOT + 196608);
  u16* wts   = (u16*)(ws + (fused ? 4*SLOT : 3*SLOT));
  u16* upd16 = fused ? (u16*)(ws + 3*SLOT) : (u16*)d_out;

  k0_cvt<<<96, 256, 0, stream>>>(W_left, W_lgate, W_right, W_rgate, W_ogate, W_out, wts);
  k1ab_proj<<<2048, 256, 0, stream>>>(z, pmask, lnw, lnb, b_lgate, b_rgate, wts,
                                      znS, left_t, right_t);
  k2_einsum<<<dim3(4,4,128), 256, 0, stream>>>(left_t, right_t, upd16);

  if (fused){
    k3bf_out<<<4096, 256, 0, stream>>>(upd16, znS, pmask, onw, onb, b_ogate, wts,
                                       (float*)d_out);
  } else {
    k3a_ln<<<dim3(512,4), 256, 0, stream>>>(upd16, onw, onb, left_t /*znu*/);
    k3b_out<<<4096, 256, 0, stream>>>(left_t /*znu*/, znS, pmask, b_ogate, wts,
                                      (float*)d_out);
  }
}